// Round 9
// baseline (30.680 us; speedup 1.0000x reference)
//
#include <hip/hip_runtime.h>

// ---------------- problem constants ----------------
#define DTSTEP  3600.0
#define T_STEPS 1048576
#define LCH     8                     // u-rows per chunk (one chunk per thread)
#define TPB     512                   // threads per block (8 waves)
#define NBLK    256                   // block = 4096 steps; 256 blocks <= 256 CUs (co-resident)
#define MAGIC   0x51CAFE17u
#define RECU    11                    // u record stride in float4 (10 data + 1 pad, 16B-aligned)
#define RECX    7                     // xsol record stride in float4 (6 data + 1 pad)

// sPW[r] = M^(2^(r+3)), r=0..16:
//   r=0..5  intra-wave scan + per-lane offset M^(8l)
//   r=6..8  cross-wave scan + per-wave offset M^(512w)
//   r=9..16 cross-block weights M^(4096*2^r)
// ws: aggregates float[256*3] at 0; flags uint[256] at float-offset 1024.

__device__ inline void matsq3(double* C){
  double R[9];
#pragma unroll
  for (int r=0;r<3;r++){
#pragma unroll
    for (int c=0;c<3;c++){
      R[r*3+c] = C[r*3+0]*C[0+c] + C[r*3+1]*C[3+c] + C[r*3+2]*C[6+c];
    }
  }
#pragma unroll
  for (int k=0;k<9;k++) C[k]=R[k];
}

__device__ void setup_from_rc(const float* __restrict__ rc,
                              float* __restrict__ sMN, float* __restrict__ sPW){
  const float Rg = rc[0]*10.f+1.f, Ri = rc[1]*10.f+1.f, Re = rc[2]*10.f+1.f, Rw = rc[3]*10.f+1.f;
  const float Cai = rc[4]*1e6f+1e5f, Cwe = rc[5]*1e6f+1e5f, Cwi = rc[6]*1e6f+1e5f;
  double Md[9];
  Md[0] = 1.0 + DTSTEP*(-(1.0/Rg + 1.0/Ri)/Cai);
  Md[1] = 0.0;
  Md[2] = DTSTEP*(1.0/((double)Ri*(double)Cai));
  Md[3] = 0.0;
  Md[4] = 1.0 + DTSTEP*(-(1.0/Re + 1.0/Rw)/Cwe);
  Md[5] = DTSTEP*(1.0/((double)Rw*(double)Cwe));
  Md[6] = DTSTEP*(1.0/((double)Ri*(double)Cwi));
  Md[7] = DTSTEP*(1.0/((double)Rw*(double)Cwi));
  Md[8] = 1.0 + DTSTEP*(-(1.0/Rw + 1.0/Ri)/Cwi);
  sMN[0]=(float)Md[0]; sMN[1]=(float)Md[2]; sMN[2]=(float)Md[4]; sMN[3]=(float)Md[5];
  sMN[4]=(float)Md[6]; sMN[5]=(float)Md[7]; sMN[6]=(float)Md[8];
  sMN[7] =(float)(DTSTEP*(1.0/((double)Rg*(double)Cai)));   // N0
  sMN[8] =(float)(DTSTEP*(1.0/(double)Cai));                // N1
  sMN[9] =(float)(DTSTEP*(1.0/(double)Cai));                // N2
  sMN[10]=(float)(DTSTEP*(1.0/((double)Re*(double)Cwe)));   // N5
  sMN[11]=(float)(DTSTEP*(1.0/(double)Cwe));                // N8
  sMN[12]=(float)(DTSTEP*(1.0/(double)Cwi));                // N14
  double C[9];
#pragma unroll
  for (int k=0;k<9;k++) C[k]=Md[k];
  for (int k=1;k<=19;k++){
    matsq3(C);                                   // C = M^(2^k)
    if (k>=3){
#pragma unroll
      for (int j=0;j<9;j++) sPW[(k-3)*9+j] = (float)C[j];
    }
  }
}

struct MN { float M0,M2,M4,M5,M6,M7,M8, N0,N1,N2,N5,N8,N14; };

__device__ inline MN mn_from_lds(const float* __restrict__ sMN){
  MN p;
  p.M0=sMN[0]; p.M2=sMN[1]; p.M4=sMN[2]; p.M5=sMN[3];
  p.M6=sMN[4]; p.M7=sMN[5]; p.M8=sMN[6];
  p.N0=sMN[7]; p.N1=sMN[8]; p.N2=sMN[9];
  p.N5=sMN[10]; p.N8=sMN[11]; p.N14=sMN[12];
  return p;
}

__device__ inline void chunk_v(const float* uu, const MN& mn, float& v0, float& v1, float& v2){
  v0=0.f; v1=0.f; v2=0.f;
#pragma unroll
  for (int j=0;j<LCH;j++){
    const float u0=uu[j*5+0],u1=uu[j*5+1],u2=uu[j*5+2],u3=uu[j*5+3],u4v=uu[j*5+4];
    const float c0 = fmaf(mn.N0,u0, fmaf(mn.N1,u1, mn.N2*u2));
    const float c1 = fmaf(mn.N5,u0, mn.N8*u3);
    const float c2 = mn.N14*u4v;
    const float n0 = fmaf(mn.M0,v0, fmaf(mn.M2,v2, c0));
    const float n1 = fmaf(mn.M4,v1, fmaf(mn.M5,v2, c1));
    const float n2 = fmaf(mn.M6,v0, fmaf(mn.M7,v1, fmaf(mn.M8,v2, c2)));
    v0=n0; v1=n1; v2=n2;
  }
}

template<int BASE, int NBITS>
__device__ inline void apply_pw(const float* __restrict__ sPW, unsigned e,
                                float& x0, float& x1, float& x2){
#pragma unroll
  for (int r=0;r<NBITS;r++){
    if (e & (1u<<r)){
      const float* Q = &sPW[(BASE+r)*9];
      const float y0 = fmaf(Q[0],x0, fmaf(Q[1],x1, Q[2]*x2));
      const float y1 = fmaf(Q[3],x0, fmaf(Q[4],x1, Q[5]*x2));
      const float y2 = fmaf(Q[6],x0, fmaf(Q[7],x1, Q[8]*x2));
      x0=y0; x1=y1; x2=y2;
    }
  }
}

__global__ __launch_bounds__(TPB) void k_fused(const float* __restrict__ u,
                                               const float* __restrict__ rc,
                                               const float* __restrict__ x_init,
                                               float* __restrict__ wsAgg,
                                               unsigned int* __restrict__ wsFlag,
                                               float* __restrict__ out){
  __shared__ float sMN[13];
  __shared__ float sPW[17*9];
  __shared__ float4 sU[8*64*RECU];   // 88KB per-wave staging (u in, then xsol out)
  __shared__ float wagg[8][3];
  __shared__ float woff[8][3];
  __shared__ float partial[8][3];
  const int tid  = threadIdx.x;
  const int blk  = blockIdx.x;
  const int lane = tid & 63;
  const int wid  = tid >> 6;
  const int i    = blk*TPB + tid;                // chunk id

  // ---- coalesced u load: each instruction reads one contiguous 1KB segment ----
  const float4* gu = reinterpret_cast<const float4*>(u)
                   + ((size_t)blk*TPB + (size_t)wid*64)*10;
  float4 g[10];
#pragma unroll
  for (int k=0;k<10;k++) g[k] = gu[k*64 + lane];
  if (tid==0) setup_from_rc(rc, sMN, sPW);       // overlaps with loads in flight
  // ---- stage into per-wave LDS region (record stride RECU float4s) ----
  float4* wu = &sU[(size_t)wid*64*RECU];
#pragma unroll
  for (int k=0;k<10;k++){
    const int f = k*64 + lane;                   // flat float4 idx in wave's 10KB
    wu[(f/10)*RECU + (f%10)] = g[k];
  }
  // ---- each lane reads its own 160B record (wave-ordered DS, no barrier) ----
  float uu[LCH*5];
#pragma unroll
  for (int q=0;q<10;q++){
    const float4 v = wu[lane*RECU + q];
    uu[q*4+0]=v.x; uu[q*4+1]=v.y; uu[q*4+2]=v.z; uu[q*4+3]=v.w;
  }
  __syncthreads();                                                  // B1 (sPW ready)
  const MN mn = mn_from_lds(sMN);
  float L0,L1,L2;
  chunk_v(uu, mn, L0,L1,L2);
  // ---- intra-wave inclusive affine scan (6 shfl rounds, barrier-free) ----
#pragma unroll
  for (int r=0;r<6;r++){
    const int d = 1<<r;
    const float* Q = &sPW[r*9];
    const float p0=__shfl_up(L0,(unsigned)d,64);
    const float p1=__shfl_up(L1,(unsigned)d,64);
    const float p2=__shfl_up(L2,(unsigned)d,64);
    if (lane >= d){
      const float y0 = fmaf(Q[0],p0, fmaf(Q[1],p1, fmaf(Q[2],p2, L0)));
      const float y1 = fmaf(Q[3],p0, fmaf(Q[4],p1, fmaf(Q[5],p2, L1)));
      const float y2 = fmaf(Q[6],p0, fmaf(Q[7],p1, fmaf(Q[8],p2, L2)));
      L0=y0; L1=y1; L2=y2;
    }
  }
  if (lane==63){ wagg[wid][0]=L0; wagg[wid][1]=L1; wagg[wid][2]=L2; }
  __syncthreads();                                                  // B2
  // ---- cross-wave scan over 8 aggregates (wave 0); publish block aggregate early ----
  if (wid==0){
    float a0=0.f,a1=0.f,a2=0.f;
    if (lane<8){ a0=wagg[lane][0]; a1=wagg[lane][1]; a2=wagg[lane][2]; }
#pragma unroll
    for (int r=0;r<3;r++){
      const int d = 1<<r;
      const float* Q = &sPW[(6+r)*9];
      const float p0=__shfl_up(a0,(unsigned)d,64);
      const float p1=__shfl_up(a1,(unsigned)d,64);
      const float p2=__shfl_up(a2,(unsigned)d,64);
      if (lane>=d && lane<8){
        const float y0 = fmaf(Q[0],p0, fmaf(Q[1],p1, fmaf(Q[2],p2, a0)));
        const float y1 = fmaf(Q[3],p0, fmaf(Q[4],p1, fmaf(Q[5],p2, a1)));
        const float y2 = fmaf(Q[6],p0, fmaf(Q[7],p1, fmaf(Q[8],p2, a2)));
        a0=y0; a1=y1; a2=y2;
      }
    }
    if (lane==7){
      __hip_atomic_store(&wsAgg[blk*3+0], a0, __ATOMIC_RELAXED, __HIP_MEMORY_SCOPE_AGENT);
      __hip_atomic_store(&wsAgg[blk*3+1], a1, __ATOMIC_RELAXED, __HIP_MEMORY_SCOPE_AGENT);
      __hip_atomic_store(&wsAgg[blk*3+2], a2, __ATOMIC_RELAXED, __HIP_MEMORY_SCOPE_AGENT);
      __hip_atomic_store(&wsFlag[blk], MAGIC, __ATOMIC_RELEASE, __HIP_MEMORY_SCOPE_AGENT);
    }
    if (lane<8){ woff[lane][0]=a0; woff[lane][1]=a1; woff[lane][2]=a2; }
  }
  __syncthreads();                                                  // B3
  // ---- block start S = M^(4096*blk) x_init + sum_{j<blk} M^(4096*(blk-1-j)) agg_j ----
  float c0=0.f, c1=0.f, c2=0.f;
  if (tid < blk){
    while (__hip_atomic_load(&wsFlag[tid], __ATOMIC_RELAXED, __HIP_MEMORY_SCOPE_AGENT) != MAGIC)
      __builtin_amdgcn_s_sleep(2);
    (void)__hip_atomic_load(&wsFlag[tid], __ATOMIC_ACQUIRE, __HIP_MEMORY_SCOPE_AGENT);
    c0=__hip_atomic_load(&wsAgg[tid*3+0], __ATOMIC_RELAXED, __HIP_MEMORY_SCOPE_AGENT);
    c1=__hip_atomic_load(&wsAgg[tid*3+1], __ATOMIC_RELAXED, __HIP_MEMORY_SCOPE_AGENT);
    c2=__hip_atomic_load(&wsAgg[tid*3+2], __ATOMIC_RELAXED, __HIP_MEMORY_SCOPE_AGENT);
    apply_pw<9,8>(sPW, (unsigned)(blk-1-tid), c0,c1,c2);
  } else if (tid==TPB-1){
    c0=x_init[0]; c1=x_init[1]; c2=x_init[2];
    apply_pw<9,8>(sPW, (unsigned)blk, c0,c1,c2);
  }
#pragma unroll
  for (int off=32; off>0; off>>=1){
    c0 += __shfl_down(c0, (unsigned)off, 64);
    c1 += __shfl_down(c1, (unsigned)off, 64);
    c2 += __shfl_down(c2, (unsigned)off, 64);
  }
  if (lane==0){ partial[wid][0]=c0; partial[wid][1]=c1; partial[wid][2]=c2; }
  __syncthreads();                                                  // B4
  float S0=0.f,S1=0.f,S2=0.f;
#pragma unroll
  for (int w=0;w<8;w++){ S0+=partial[w][0]; S1+=partial[w][1]; S2+=partial[w][2]; }
  // ---- chunk start: x = M^(8*lane) * (M^(512*wid) S + W_{wid-1}) + L_{tid-1} ----
  float x0=S0, x1=S1, x2=S2;
  apply_pw<6,3>(sPW, (unsigned)wid, x0,x1,x2);
  if (wid>0){ x0+=woff[wid-1][0]; x1+=woff[wid-1][1]; x2+=woff[wid-1][2]; }
  apply_pw<0,6>(sPW, (unsigned)lane, x0,x1,x2);
  {
    const float q0=__shfl_up(L0,1u,64);
    const float q1=__shfl_up(L1,1u,64);
    const float q2=__shfl_up(L2,1u,64);
    if (lane>0){ x0+=q0; x1+=q1; x2+=q2; }
  }
  // ---- replay 8 steps ----
  float px[LCH*3], py[LCH];
#pragma unroll
  for (int j=0;j<LCH;j++){
    py[j]=x0;                                    // y_t = C x_t (pre-update)
    const float u0=uu[j*5+0],u1=uu[j*5+1],u2=uu[j*5+2],u3=uu[j*5+3],u4v=uu[j*5+4];
    const float d0 = fmaf(mn.N0,u0, fmaf(mn.N1,u1, mn.N2*u2));
    const float d1 = fmaf(mn.N5,u0, mn.N8*u3);
    const float d2 = mn.N14*u4v;
    const float n0 = fmaf(mn.M0,x0, fmaf(mn.M2,x2, d0));
    const float n1 = fmaf(mn.M4,x1, fmaf(mn.M5,x2, d1));
    const float n2 = fmaf(mn.M6,x0, fmaf(mn.M7,x1, fmaf(mn.M8,x2, d2)));
    x0=n0; x1=n1; x2=n2;
    px[j*3+0]=x0; px[j*3+1]=x1; px[j*3+2]=x2;    // xsol_t = x_{t+1}
  }
  // ---- xsol: stage per-wave into LDS (stride RECX), then coalesced copy-out ----
  float4* wx = &sU[(size_t)wid*64*RECU];         // reuse staging region (wave-ordered DS)
#pragma unroll
  for (int m=0;m<6;m++)
    wx[lane*RECX + m] = make_float4(px[4*m+0],px[4*m+1],px[4*m+2],px[4*m+3]);
  float4* xg = reinterpret_cast<float4*>(out) + ((size_t)blk*TPB + (size_t)wid*64)*6;
#pragma unroll
  for (int k=0;k<6;k++){
    const int f = k*64 + lane;                   // flat float4 idx in wave's 6KB
    xg[f] = wx[(f/6)*RECX + (f%6)];
  }
  // ---- ysol: direct (stride-32B, 2 lanes/line — adequately coalesced) ----
  float4* yo4 = reinterpret_cast<float4*>(out) + (size_t)(3*T_STEPS/4) + (size_t)i*2;
  yo4[0] = make_float4(py[0],py[1],py[2],py[3]);
  yo4[1] = make_float4(py[4],py[5],py[6],py[7]);
}

extern "C" void kernel_launch(void* const* d_in, const int* in_sizes, int n_in,
                              void* d_out, int out_size, void* d_ws, size_t ws_size,
                              hipStream_t stream) {
  (void)out_size; (void)ws_size;
  const float* x_init = (const float*)d_in[0];
  const float* u      = (const float*)d_in[1];
  const float* rc     = (const float*)d_in[2];
  for (int k=0;k<n_in;k++){
    if (in_sizes[k]==3) x_init = (const float*)d_in[k];
    else if (in_sizes[k]==7) rc = (const float*)d_in[k];
    else if (in_sizes[k]==T_STEPS*5) u = (const float*)d_in[k];
  }
  float* wsAgg = (float*)d_ws;                                  // 256*3 floats
  unsigned int* wsFlag = (unsigned int*)((float*)d_ws + 1024);  // 256 flags
  float* out = (float*)d_out;

  k_fused<<<NBLK, TPB, 0, stream>>>(u, rc, x_init, wsAgg, wsFlag, out);
}

// Round 10
// 28.330 us; speedup vs baseline: 1.0829x; 1.0829x over previous
//
#include <hip/hip_runtime.h>

// ---------------- problem constants ----------------
#define DTSTEP  3600.0
#define T_STEPS 1048576
#define LCH     4                     // u-rows per chunk (one chunk per thread)
#define TPB     512                   // threads per block
#define NBLK    512                   // block = 2048 steps; 2 blocks/CU -> 16 waves/CU
#define NAGG    NBLK                  // block aggregates (== TPB)

// sPW[k-2] = M^(2^k) as f32, k=2..19 (18 matrices):
//   intra-block scan round r (d=2^r chunks of 4 steps): sPW[r],   r=0..8
//   aggregate  scan round r (d=2^r blocks of 2048):     sPW[9+r], r=0..8
//   chunk transition P = M^4 = sPW[0]; block transition R = M^2048 = sPW[9]
// ws: 512 block aggregates (3 floats) = 6 KB

__device__ inline void matsq3(double* C){
  double R[9];
#pragma unroll
  for (int r=0;r<3;r++){
#pragma unroll
    for (int c=0;c<3;c++){
      R[r*3+c] = C[r*3+0]*C[0+c] + C[r*3+1]*C[3+c] + C[r*3+2]*C[6+c];
    }
  }
#pragma unroll
  for (int k=0;k<9;k++) C[k]=R[k];
}

// thread-0-per-block: build M,N (f32) + 18 matrix powers via f64 squaring
__device__ void setup_from_rc(const float* __restrict__ rc,
                              float* __restrict__ sMN, float* __restrict__ sPW){
  const float Rg = rc[0]*10.f+1.f, Ri = rc[1]*10.f+1.f, Re = rc[2]*10.f+1.f, Rw = rc[3]*10.f+1.f;
  const float Cai = rc[4]*1e6f+1e5f, Cwe = rc[5]*1e6f+1e5f, Cwi = rc[6]*1e6f+1e5f;
  double Md[9];
  Md[0] = 1.0 + DTSTEP*(-(1.0/Rg + 1.0/Ri)/Cai);
  Md[1] = 0.0;
  Md[2] = DTSTEP*(1.0/((double)Ri*(double)Cai));
  Md[3] = 0.0;
  Md[4] = 1.0 + DTSTEP*(-(1.0/Re + 1.0/Rw)/Cwe);
  Md[5] = DTSTEP*(1.0/((double)Rw*(double)Cwe));
  Md[6] = DTSTEP*(1.0/((double)Ri*(double)Cwi));
  Md[7] = DTSTEP*(1.0/((double)Rw*(double)Cwi));
  Md[8] = 1.0 + DTSTEP*(-(1.0/Rw + 1.0/Ri)/Cwi);
  sMN[0]=(float)Md[0]; sMN[1]=(float)Md[2]; sMN[2]=(float)Md[4]; sMN[3]=(float)Md[5];
  sMN[4]=(float)Md[6]; sMN[5]=(float)Md[7]; sMN[6]=(float)Md[8];
  sMN[7] =(float)(DTSTEP*(1.0/((double)Rg*(double)Cai)));   // N0
  sMN[8] =(float)(DTSTEP*(1.0/(double)Cai));                // N1
  sMN[9] =(float)(DTSTEP*(1.0/(double)Cai));                // N2
  sMN[10]=(float)(DTSTEP*(1.0/((double)Re*(double)Cwe)));   // N5
  sMN[11]=(float)(DTSTEP*(1.0/(double)Cwe));                // N8
  sMN[12]=(float)(DTSTEP*(1.0/(double)Cwi));                // N14
  double C[9];
#pragma unroll
  for (int k=0;k<9;k++) C[k]=Md[k];
  for (int k=1;k<=19;k++){
    matsq3(C);                                   // C = M^(2^k)
    if (k>=2){
#pragma unroll
      for (int j=0;j<9;j++) sPW[(k-2)*9+j] = (float)C[j];
    }
  }
}

struct MN { float M0,M2,M4,M5,M6,M7,M8, N0,N1,N2,N5,N8,N14; };

__device__ inline MN mn_from_lds(const float* __restrict__ sMN){
  MN p;
  p.M0=sMN[0]; p.M2=sMN[1]; p.M4=sMN[2]; p.M5=sMN[3];
  p.M6=sMN[4]; p.M7=sMN[5]; p.M8=sMN[6];
  p.N0=sMN[7]; p.N1=sMN[8]; p.N2=sMN[9];
  p.N5=sMN[10]; p.N8=sMN[11]; p.N14=sMN[12];
  return p;
}

// v <- M v + N u_j over the chunk (exploits exact zeros in M,N)
__device__ inline void chunk_v(const float* uu, const MN& mn, float& v0, float& v1, float& v2){
  v0=0.f; v1=0.f; v2=0.f;
#pragma unroll
  for (int j=0;j<LCH;j++){
    const float u0=uu[j*5+0],u1=uu[j*5+1],u2=uu[j*5+2],u3=uu[j*5+3],u4v=uu[j*5+4];
    const float c0 = fmaf(mn.N0,u0, fmaf(mn.N1,u1, mn.N2*u2));
    const float c1 = fmaf(mn.N5,u0, mn.N8*u3);
    const float c2 = mn.N14*u4v;
    const float n0 = fmaf(mn.M0,v0, fmaf(mn.M2,v2, c0));
    const float n1 = fmaf(mn.M4,v1, fmaf(mn.M5,v2, c1));
    const float n2 = fmaf(mn.M6,v0, fmaf(mn.M7,v1, fmaf(mn.M8,v2, c2)));
    v0=n0; v1=n1; v2=n2;
  }
}

// K1: per-chunk v, 512-wide LDS affine scan -> block aggregate ws[blk]
__global__ __launch_bounds__(TPB) void k_agg(const float* __restrict__ u,
                                             const float* __restrict__ rc,
                                             float* __restrict__ ws){
  __shared__ float sMN[13];
  __shared__ float sPW[18*9];
  __shared__ float buf[2][TPB*3];
  const int tid = threadIdx.x;
  const int blk = blockIdx.x;
  const int i   = blk*TPB + tid;                 // chunk id
  float uu[LCH*5];
  const float4* u4 = reinterpret_cast<const float4*>(u) + (size_t)i*(LCH*5/4);
#pragma unroll
  for (int k=0;k<LCH*5/4;k++){
    const float4 q = u4[k];
    uu[k*4+0]=q.x; uu[k*4+1]=q.y; uu[k*4+2]=q.z; uu[k*4+3]=q.w;
  }
  if (tid==0) setup_from_rc(rc, sMN, sPW);
  __syncthreads();
  const MN mn = mn_from_lds(sMN);
  float t0,t1,t2;
  chunk_v(uu, mn, t0,t1,t2);
  buf[0][tid*3+0]=t0; buf[0][tid*3+1]=t1; buf[0][tid*3+2]=t2;
  __syncthreads();
  int cur=0;
#pragma unroll
  for (int r=0;r<9;r++){
    const int d = 1<<r;
    const float Q0=sPW[r*9+0],Q1=sPW[r*9+1],Q2=sPW[r*9+2],
                Q3=sPW[r*9+3],Q4=sPW[r*9+4],Q5=sPW[r*9+5],
                Q6=sPW[r*9+6],Q7=sPW[r*9+7],Q8=sPW[r*9+8];
    float p0=0.f,p1=0.f,p2=0.f;
    if (tid >= d){
      const int s=(tid-d)*3;
      p0=buf[cur][s+0]; p1=buf[cur][s+1]; p2=buf[cur][s+2];
    }
    t0 = fmaf(Q0,p0, fmaf(Q1,p1, fmaf(Q2,p2, t0)));
    t1 = fmaf(Q3,p0, fmaf(Q4,p1, fmaf(Q5,p2, t1)));
    t2 = fmaf(Q6,p0, fmaf(Q7,p1, fmaf(Q8,p2, t2)));
    buf[cur^1][tid*3+0]=t0; buf[cur^1][tid*3+1]=t1; buf[cur^1][tid*3+2]=t2;
    __syncthreads();
    cur ^= 1;
  }
  if (tid==TPB-1){
    ws[blk*3+0]=t0; ws[blk*3+1]=t1; ws[blk*3+2]=t2;
  }
}

// K2: redundant per-block scan of 512 aggregates -> block start; recompute chunk_v;
// 512-wide scan -> exact chunk starts; replay 4 steps; f32 float4 outputs.
__global__ __launch_bounds__(TPB) void k_expand(const float* __restrict__ u,
                                                const float* __restrict__ rc,
                                                const float* __restrict__ x_init,
                                                const float* __restrict__ ws,
                                                float* __restrict__ out){
  __shared__ float sMN[13];
  __shared__ float sPW[18*9];
  __shared__ float abuf[2][NAGG*3];
  __shared__ float buf[2][TPB*3];
  const int tid = threadIdx.x;
  const int blk = blockIdx.x;
  const int i   = blk*TPB + tid;                 // chunk id
  float uu[LCH*5];
  const float4* u4 = reinterpret_cast<const float4*>(u) + (size_t)i*(LCH*5/4);
#pragma unroll
  for (int k=0;k<LCH*5/4;k++){
    const float4 q = u4[k];
    uu[k*4+0]=q.x; uu[k*4+1]=q.y; uu[k*4+2]=q.z; uu[k*4+3]=q.w;
  }
  if (tid==0) setup_from_rc(rc, sMN, sPW);
  __syncthreads();
  const float xi0=x_init[0], xi1=x_init[1], xi2=x_init[2];
  // ---- redundant aggregate scan over 512 block aggregates (all threads) ----
  float a0=ws[tid*3+0], a1=ws[tid*3+1], a2=ws[tid*3+2];
  if (tid==0){                                   // fold x_init: state after block 0
    const float R0=sPW[9*9+0],R1=sPW[9*9+1],R2=sPW[9*9+2],
                R3=sPW[9*9+3],R4=sPW[9*9+4],R5=sPW[9*9+5],
                R6=sPW[9*9+6],R7=sPW[9*9+7],R8=sPW[9*9+8];
    a0 = fmaf(R0,xi0, fmaf(R1,xi1, fmaf(R2,xi2, a0)));
    a1 = fmaf(R3,xi0, fmaf(R4,xi1, fmaf(R5,xi2, a1)));
    a2 = fmaf(R6,xi0, fmaf(R7,xi1, fmaf(R8,xi2, a2)));
  }
  abuf[0][tid*3+0]=a0; abuf[0][tid*3+1]=a1; abuf[0][tid*3+2]=a2;
  __syncthreads();
  int cur=0;
#pragma unroll
  for (int r=0;r<9;r++){
    const int d = 1<<r;
    const float Q0=sPW[(9+r)*9+0],Q1=sPW[(9+r)*9+1],Q2=sPW[(9+r)*9+2],
                Q3=sPW[(9+r)*9+3],Q4=sPW[(9+r)*9+4],Q5=sPW[(9+r)*9+5],
                Q6=sPW[(9+r)*9+6],Q7=sPW[(9+r)*9+7],Q8=sPW[(9+r)*9+8];
    float p0=0.f,p1=0.f,p2=0.f;
    if (tid >= d){
      const int s=(tid-d)*3;
      p0=abuf[cur][s+0]; p1=abuf[cur][s+1]; p2=abuf[cur][s+2];
    }
    a0 = fmaf(Q0,p0, fmaf(Q1,p1, fmaf(Q2,p2, a0)));
    a1 = fmaf(Q3,p0, fmaf(Q4,p1, fmaf(Q5,p2, a1)));
    a2 = fmaf(Q6,p0, fmaf(Q7,p1, fmaf(Q8,p2, a2)));
    abuf[cur^1][tid*3+0]=a0; abuf[cur^1][tid*3+1]=a1; abuf[cur^1][tid*3+2]=a2;
    __syncthreads();
    cur ^= 1;
  }
  // block start state
  float S0,S1,S2;
  if (blk==0){ S0=xi0; S1=xi1; S2=xi2; }
  else { const int s=(blk-1)*3; S0=abuf[cur][s+0]; S1=abuf[cur][s+1]; S2=abuf[cur][s+2]; }
  // ---- intra-block: chunk_v, fold S into chunk 0, 512-wide scan ----
  const MN mn = mn_from_lds(sMN);
  float t0,t1,t2;
  chunk_v(uu, mn, t0,t1,t2);
  if (tid==0){
    const float P0=sPW[0],P1=sPW[1],P2=sPW[2],
                P3=sPW[3],P4=sPW[4],P5=sPW[5],
                P6=sPW[6],P7=sPW[7],P8=sPW[8];
    const float b0 = fmaf(P0,S0, fmaf(P1,S1, fmaf(P2,S2, t0)));
    const float b1 = fmaf(P3,S0, fmaf(P4,S1, fmaf(P5,S2, t1)));
    const float b2 = fmaf(P6,S0, fmaf(P7,S1, fmaf(P8,S2, t2)));
    t0=b0; t1=b1; t2=b2;
  }
  buf[0][tid*3+0]=t0; buf[0][tid*3+1]=t1; buf[0][tid*3+2]=t2;
  __syncthreads();
  cur=0;
#pragma unroll
  for (int r=0;r<9;r++){
    const int d = 1<<r;
    const float Q0=sPW[r*9+0],Q1=sPW[r*9+1],Q2=sPW[r*9+2],
                Q3=sPW[r*9+3],Q4=sPW[r*9+4],Q5=sPW[r*9+5],
                Q6=sPW[r*9+6],Q7=sPW[r*9+7],Q8=sPW[r*9+8];
    float p0=0.f,p1=0.f,p2=0.f;
    if (tid >= d){
      const int s=(tid-d)*3;
      p0=buf[cur][s+0]; p1=buf[cur][s+1]; p2=buf[cur][s+2];
    }
    t0 = fmaf(Q0,p0, fmaf(Q1,p1, fmaf(Q2,p2, t0)));
    t1 = fmaf(Q3,p0, fmaf(Q4,p1, fmaf(Q5,p2, t1)));
    t2 = fmaf(Q6,p0, fmaf(Q7,p1, fmaf(Q8,p2, t2)));
    buf[cur^1][tid*3+0]=t0; buf[cur^1][tid*3+1]=t1; buf[cur^1][tid*3+2]=t2;
    __syncthreads();
    cur ^= 1;
  }
  // chunk start = previous thread's inclusive value; tid 0 -> S
  float x0,x1,x2;
  if (tid==0){ x0=S0; x1=S1; x2=S2; }
  else { const int s=(tid-1)*3; x0=buf[cur][s+0]; x1=buf[cur][s+1]; x2=buf[cur][s+2]; }
  // ---- replay 4 steps, write f32 outputs ----
  float px[LCH*3], py[LCH];
#pragma unroll
  for (int j=0;j<LCH;j++){
    py[j]=x0;                                    // y_t = C x_t (pre-update)
    const float u0=uu[j*5+0],u1=uu[j*5+1],u2=uu[j*5+2],u3=uu[j*5+3],u4v=uu[j*5+4];
    const float c0 = fmaf(mn.N0,u0, fmaf(mn.N1,u1, mn.N2*u2));
    const float c1 = fmaf(mn.N5,u0, mn.N8*u3);
    const float c2 = mn.N14*u4v;
    const float n0 = fmaf(mn.M0,x0, fmaf(mn.M2,x2, c0));
    const float n1 = fmaf(mn.M4,x1, fmaf(mn.M5,x2, c1));
    const float n2 = fmaf(mn.M6,x0, fmaf(mn.M7,x1, fmaf(mn.M8,x2, c2)));
    x0=n0; x1=n1; x2=n2;
    px[j*3+0]=x0; px[j*3+1]=x1; px[j*3+2]=x2;    // xsol_t = x_{t+1}
  }
  float4* xo4 = reinterpret_cast<float4*>(out) + (size_t)i*3;
  xo4[0] = make_float4(px[0],px[1],px[ 2],px[ 3]);
  xo4[1] = make_float4(px[4],px[5],px[ 6],px[ 7]);
  xo4[2] = make_float4(px[8],px[9],px[10],px[11]);
  float4* yo4 = reinterpret_cast<float4*>(out) + (size_t)(3*T_STEPS/4) + (size_t)i;
  yo4[0] = make_float4(py[0],py[1],py[2],py[3]);
}

extern "C" void kernel_launch(void* const* d_in, const int* in_sizes, int n_in,
                              void* d_out, int out_size, void* d_ws, size_t ws_size,
                              hipStream_t stream) {
  (void)out_size; (void)ws_size;
  const float* x_init = (const float*)d_in[0];
  const float* u      = (const float*)d_in[1];
  const float* rc     = (const float*)d_in[2];
  for (int k=0;k<n_in;k++){
    if (in_sizes[k]==3) x_init = (const float*)d_in[k];
    else if (in_sizes[k]==7) rc = (const float*)d_in[k];
    else if (in_sizes[k]==T_STEPS*5) u = (const float*)d_in[k];
  }
  float* ws  = (float*)d_ws;                // 512 aggregates × 3 floats = 6 KB
  float* out = (float*)d_out;               // f32 outputs

  k_agg   <<<NBLK, TPB, 0, stream>>>(u, rc, ws);
  k_expand<<<NBLK, TPB, 0, stream>>>(u, rc, x_init, ws, out);
}